// Round 2
// baseline (3024.648 us; speedup 1.0000x reference)
//
#include <hip/hip_runtime.h>
#include <math.h>

// ---------------------------------------------------------------------------
// Swin block: B=64 H=W=56 C=256 WIN=7 SHIFT=3 HEADS=8 HD=32.
// Input/output dtype (fp32 vs bf16) detected at runtime from x's bit patterns;
// internal pipeline is bf16 MFMA throughout.
// ---------------------------------------------------------------------------

typedef __attribute__((ext_vector_type(8))) short bf16x8;   // 8 bf16 = 4 VGPRs
typedef __attribute__((ext_vector_type(4))) float f32x4;

#define NTOK 200704   // 64*56*56
#define NN   49
#define NPARAM 4680   // fp32 param block element count

__device__ __forceinline__ float bf2f(unsigned short u) {
    union { unsigned int i; float f; } v; v.i = ((unsigned)u) << 16; return v.f;
}
__device__ __forceinline__ unsigned short f2bf(float f) {
    union { float fv; unsigned int i; } v; v.fv = f;
    return (unsigned short)((v.i + 0x7fffu + ((v.i >> 16) & 1u)) >> 16);  // RNE
}

// ------------------------------ dtype detector -----------------------------
// flag=1 -> inputs are fp32; flag=0 -> inputs are bf16.
// Even-index ushorts of a bf16 N(0,1) array have sane exponents; of an fp32
// array they are mantissa halves (uniform random or zero).
__global__ void detect_kernel(const unsigned short* __restrict__ xu, int* flag) {
    int ln = threadIdx.x;  // 64 threads
    int sane = 0;
    #pragma unroll
    for (int t = 0; t < 16; t++) {
        unsigned u = xu[(ln * 16 + t) * 2];
        unsigned e = (u >> 7) & 0xFF;
        sane += (e >= 0x60 && e <= 0x90) ? 1 : 0;
    }
    #pragma unroll
    for (int off = 32; off; off >>= 1) sane += __shfl_xor(sane, off);
    if (ln == 0) *flag = (sane < 614) ? 1 : 0;
}

__device__ __forceinline__ float ld_any(const void* p, int j, int f) {
    return f ? ((const float*)p)[j] : bf2f(((const unsigned short*)p)[j]);
}

// ------------------------ small params -> fp32 block -----------------------
__global__ void convert_params_kernel(
    const void* ln1_g, const void* ln1_b, const void* qkv_b, const void* proj_b,
    const void* ln2_g, const void* ln2_b, const void* b1, const void* b2,
    const void* rpb, const int* __restrict__ flag, float* __restrict__ dst) {
    int i = blockIdx.x * 256 + threadIdx.x;
    if (i >= NPARAM) return;
    int f = *flag;
    const void* src; int j;
    if      (i < 256)  { src = ln1_g;  j = i; }
    else if (i < 512)  { src = ln1_b;  j = i - 256; }
    else if (i < 1280) { src = qkv_b;  j = i - 512; }
    else if (i < 1536) { src = proj_b; j = i - 1280; }
    else if (i < 1792) { src = ln2_g;  j = i - 1536; }
    else if (i < 2048) { src = ln2_b;  j = i - 1792; }
    else if (i < 3072) { src = b1;     j = i - 2048; }
    else if (i < 3328) { src = b2;     j = i - 3072; }
    else               { src = rpb;    j = i - 3328; }
    dst[i] = ld_any(src, j, f);
}

// --------------------- weight transpose (any dtype -> bf16) ----------------
// in: (K,N) row-major -> out: (N,K) row-major bf16
__global__ void transpose_any(const void* __restrict__ in,
                              unsigned short* __restrict__ out, int K, int N,
                              const int* __restrict__ flag) {
    int f = *flag;
    int idx = blockIdx.x * 256 + threadIdx.x;
    if (idx < K * N) {
        int k = idx / N, n = idx - k * N;
        out[n * K + k] = f2bf(ld_any(in, idx, f));
    }
}

// ------------------------- LN1 + shift + window partition ------------------
__global__ __launch_bounds__(256) void ln1_window_kernel(
    const void* __restrict__ x, const float* __restrict__ paramsF,
    unsigned short* __restrict__ y, const int* __restrict__ flag) {
    int f = *flag;
    int wv = threadIdx.x >> 6, ln = threadIdx.x & 63;
    int tok = blockIdx.x * 4 + wv;
    float v0, v1, v2, v3;
    if (f) {
        float4 pv = *(const float4*)((const float*)x + (size_t)tok * 256 + ln * 4);
        v0 = pv.x; v1 = pv.y; v2 = pv.z; v3 = pv.w;
    } else {
        ushort4 pv = *(const ushort4*)((const unsigned short*)x + (size_t)tok * 256 + ln * 4);
        v0 = bf2f(pv.x); v1 = bf2f(pv.y); v2 = bf2f(pv.z); v3 = bf2f(pv.w);
    }
    float s = v0 + v1 + v2 + v3;
    float sq = v0 * v0 + v1 * v1 + v2 * v2 + v3 * v3;
    #pragma unroll
    for (int off = 32; off; off >>= 1) { s += __shfl_xor(s, off); sq += __shfl_xor(sq, off); }
    float mu = s * (1.f / 256.f);
    float rs = rsqrtf(fmaxf(sq * (1.f / 256.f) - mu * mu, 0.f) + 1e-5f);
    float4 gv = *(const float4*)(paramsF + ln * 4);        // ln1_g
    float4 bv = *(const float4*)(paramsF + 256 + ln * 4);  // ln1_b
    int bb = tok / 3136, hw = tok - bb * 3136;
    int h = hw / 56, w = hw - h * 56;
    int hp = h - 3; hp += (hp < 0) ? 56 : 0;
    int wp = w - 3; wp += (wp < 0) ? 56 : 0;
    int win = (hp / 7) * 8 + (wp / 7);
    int n = (hp % 7) * 7 + (wp % 7);
    size_t drow = ((size_t)bb * 64 + win) * NN + n;
    ushort4 o;
    o.x = f2bf((v0 - mu) * rs * gv.x + bv.x);
    o.y = f2bf((v1 - mu) * rs * gv.y + bv.y);
    o.z = f2bf((v2 - mu) * rs * gv.z + bv.z);
    o.w = f2bf((v3 - mu) * rs * gv.w + bv.w);
    *(ushort4*)(y + drow * 256 + ln * 4) = o;
}

// ------------------------------ GEMM core (K=256) --------------------------
__device__ __forceinline__ void gemm_core_k256(
    const unsigned short* __restrict__ A, const unsigned short* __restrict__ Bt,
    int rowBase, int colBase, unsigned short* As, unsigned short* Bs, f32x4 acc[2][4]) {
    const int tid = threadIdx.x;
    const int wv = tid >> 6, ln = tid & 63;
    const int m16 = ln & 15, q4 = ln >> 4;
    const int ar = tid >> 1, ah = (tid & 1) * 32;
    const int br = tid >> 2, bp = (tid & 3) * 16;
    for (int kb = 0; kb < 256; kb += 64) {
        const unsigned short* ag = A + (size_t)(rowBase + ar) * 256 + kb + ah;
        unsigned short* asd = As + ar * 72 + ah;
        #pragma unroll
        for (int i = 0; i < 4; i++)
            *(bf16x8*)(asd + i * 8) = *(const bf16x8*)(ag + i * 8);
        const unsigned short* bg = Bt + (size_t)(colBase + br) * 256 + kb + bp;
        unsigned short* bsd = Bs + br * 72 + bp;
        #pragma unroll
        for (int i = 0; i < 2; i++)
            *(bf16x8*)(bsd + i * 8) = *(const bf16x8*)(bg + i * 8);
        __syncthreads();
        #pragma unroll
        for (int ks = 0; ks < 64; ks += 32) {
            bf16x8 af[2], bfr[4];
            #pragma unroll
            for (int rt = 0; rt < 2; rt++)
                af[rt] = *(const bf16x8*)(As + (wv * 32 + rt * 16 + m16) * 72 + ks + q4 * 8);
            #pragma unroll
            for (int ct = 0; ct < 4; ct++)
                bfr[ct] = *(const bf16x8*)(Bs + (ct * 16 + m16) * 72 + ks + q4 * 8);
            #pragma unroll
            for (int rt = 0; rt < 2; rt++)
                #pragma unroll
                for (int ct = 0; ct < 4; ct++)
                    acc[rt][ct] = __builtin_amdgcn_mfma_f32_16x16x32_bf16(
                        af[rt], bfr[ct], acc[rt][ct], 0, 0, 0);
        }
        __syncthreads();
    }
}

// ------------------------------- GEMM: QKV ---------------------------------
__global__ __launch_bounds__(256) void gemm_qkv_kernel(
    const unsigned short* __restrict__ A, const unsigned short* __restrict__ Bt,
    const float* __restrict__ bias,  // qkv_b fp32 (768)
    unsigned short* __restrict__ out) {
    __shared__ unsigned short As[128 * 72];
    __shared__ unsigned short Bs[64 * 72];
    const int ln = threadIdx.x & 63, wv = threadIdx.x >> 6;
    const int m16 = ln & 15, q4 = ln >> 4;
    const int rowBase = blockIdx.y * 128, colBase = blockIdx.x * 64;
    f32x4 acc[2][4];
    #pragma unroll
    for (int i = 0; i < 2; i++)
        #pragma unroll
        for (int j = 0; j < 4; j++)
            #pragma unroll
            for (int r = 0; r < 4; r++) acc[i][j][r] = 0.f;
    gemm_core_k256(A, Bt, rowBase, colBase, As, Bs, acc);
    #pragma unroll
    for (int rt = 0; rt < 2; rt++)
        #pragma unroll
        for (int ct = 0; ct < 4; ct++) {
            int col = colBase + ct * 16 + m16;
            float bs = bias[col];
            float scale = (col < 256) ? 0.17677669529663689f : 1.0f;  // q * HD^-0.5
            #pragma unroll
            for (int r = 0; r < 4; r++) {
                int row = rowBase + wv * 32 + rt * 16 + q4 * 4 + r;
                out[(size_t)row * 768 + col] = f2bf((acc[rt][ct][r] + bs) * scale);
            }
        }
}

// ------------------------- GEMM: proj + scatter + residual -----------------
__global__ __launch_bounds__(256) void gemm_proj_kernel(
    const unsigned short* __restrict__ A, const unsigned short* __restrict__ Bt,
    const float* __restrict__ bias,  // proj_b fp32
    const void* __restrict__ xin,    // x natural order (flag dtype)
    unsigned short* __restrict__ x2, const int* __restrict__ flag) {
    __shared__ unsigned short As[128 * 72];
    __shared__ unsigned short Bs[64 * 72];
    const int f = *flag;
    const int ln = threadIdx.x & 63, wv = threadIdx.x >> 6;
    const int m16 = ln & 15, q4 = ln >> 4;
    const int rowBase = blockIdx.y * 128, colBase = blockIdx.x * 64;
    f32x4 acc[2][4];
    #pragma unroll
    for (int i = 0; i < 2; i++)
        #pragma unroll
        for (int j = 0; j < 4; j++)
            #pragma unroll
            for (int r = 0; r < 4; r++) acc[i][j][r] = 0.f;
    gemm_core_k256(A, Bt, rowBase, colBase, As, Bs, acc);
    #pragma unroll
    for (int rt = 0; rt < 2; rt++)
        #pragma unroll
        for (int r = 0; r < 4; r++) {
            int row = rowBase + wv * 32 + rt * 16 + q4 * 4 + r;  // window-order token
            int win = row / NN, n = row - win * NN;
            int bb = win >> 6, wl = win & 63;
            int i7 = n / 7, j7 = n - i7 * 7;
            int hp = (wl >> 3) * 7 + i7 + 3; if (hp >= 56) hp -= 56;  // un-shift
            int wp = (wl & 7) * 7 + j7 + 3;  if (wp >= 56) wp -= 56;
            size_t drow = ((size_t)bb * 3136 + hp * 56 + wp) * 256;
            #pragma unroll
            for (int ct = 0; ct < 4; ct++) {
                int col = colBase + ct * 16 + m16;
                float v = acc[rt][ct][r] + bias[col] + ld_any(xin, drow + col, f);
                x2[drow + col] = f2bf(v);
            }
        }
}

// ------------------------------- attention ---------------------------------
__global__ __launch_bounds__(256) void attn_kernel(
    const unsigned short* __restrict__ qkv,  // (NTOK,768): [q|k|v] x head x d
    const float* __restrict__ rpbF,          // (169*8) fp32
    unsigned short* __restrict__ o) {        // (NTOK,256) window order
    __shared__ unsigned short Qs[49 * 40], Ks[49 * 40], Vs[49 * 40];
    __shared__ float S[49 * 52];
    int tid = threadIdx.x;
    int win = blockIdx.x >> 3, head = blockIdx.x & 7;
    size_t base = (size_t)win * 49 * 768 + head * 32;
    if (tid < 196) {
        int i = tid >> 2, part = (tid & 3) * 8;
        *(bf16x8*)(Qs + i * 40 + part) = *(const bf16x8*)(qkv + base + (size_t)i * 768 + part);
        *(bf16x8*)(Ks + i * 40 + part) = *(const bf16x8*)(qkv + base + 256 + (size_t)i * 768 + part);
        *(bf16x8*)(Vs + i * 40 + part) = *(const bf16x8*)(qkv + base + 512 + (size_t)i * 768 + part);
    }
    __syncthreads();
    int wl = win & 63;
    int wh0 = (wl >> 3) * 7, ww0 = (wl & 7) * 7;
    for (int e = tid; e < 2401; e += 256) {
        int i = e / 49, j = e - i * 49;
        float a = 0.f;
        #pragma unroll
        for (int dd = 0; dd < 32; dd += 8) {
            bf16x8 qv = *(const bf16x8*)(Qs + i * 40 + dd);
            bf16x8 kv = *(const bf16x8*)(Ks + j * 40 + dd);
            #pragma unroll
            for (int u = 0; u < 8; u++)
                a += bf2f((unsigned short)qv[u]) * bf2f((unsigned short)kv[u]);
        }
        int ir = i / 7, ic = i - ir * 7, jr = j / 7, jc = j - jr * 7;
        a += rpbF[((ir - jr + 6) * 13 + (ic - jc + 6)) * 8 + head];
        int hi = wh0 + ir, wi = ww0 + ic, hj = wh0 + jr, wj = ww0 + jc;
        int ci = (hi < 49 ? 0 : (hi < 53 ? 3 : 6)) + (wi < 49 ? 0 : (wi < 53 ? 1 : 2));
        int cj = (hj < 49 ? 0 : (hj < 53 ? 3 : 6)) + (wj < 49 ? 0 : (wj < 53 ? 1 : 2));
        if (ci != cj) a -= 100.f;
        S[i * 52 + j] = a;
    }
    __syncthreads();
    if (tid < 49) {
        float m = -1e30f;
        for (int j = 0; j < 49; j++) m = fmaxf(m, S[tid * 52 + j]);
        float s = 0.f;
        for (int j = 0; j < 49; j++) { float e = expf(S[tid * 52 + j] - m); S[tid * 52 + j] = e; s += e; }
        float inv = 1.f / s;
        for (int j = 0; j < 49; j++) S[tid * 52 + j] *= inv;
    }
    __syncthreads();
    if (tid < 196) {
        int i = tid >> 2, dr = (tid & 3) * 8;
        float a[8];
        #pragma unroll
        for (int u = 0; u < 8; u++) a[u] = 0.f;
        for (int j = 0; j < 49; j++) {
            float pp = S[i * 52 + j];
            bf16x8 vv = *(const bf16x8*)(Vs + j * 40 + dr);
            #pragma unroll
            for (int u = 0; u < 8; u++) a[u] += pp * bf2f((unsigned short)vv[u]);
        }
        bf16x8 ov;
        #pragma unroll
        for (int u = 0; u < 8; u++) ov[u] = (short)f2bf(a[u]);
        *(bf16x8*)(o + ((size_t)win * 49 + i) * 256 + head * 32 + dr) = ov;
    }
}

// -------------------------- fused LN2 + MLP + residual ---------------------
__global__ __launch_bounds__(256) void mlp_fused_kernel(
    const unsigned short* __restrict__ x2,
    const float* __restrict__ g2F, const float* __restrict__ b2lnF,
    const unsigned short* __restrict__ w1t, const float* __restrict__ b1F,
    const unsigned short* __restrict__ w2t, const float* __restrict__ b2F,
    void* __restrict__ out, const int* __restrict__ flag) {
    __shared__ unsigned short As2[16 * 264];
    __shared__ unsigned short Hs[16 * 1032];
    __shared__ unsigned short Bs[64 * 264];
    const int f = *flag;
    int tid = threadIdx.x;
    int wv = tid >> 6, ln = tid & 63;
    int m16 = ln & 15, q4 = ln >> 4;
    int tok0 = blockIdx.x * 16;

    // ---- LN2 of 16-token tile into As2 ----
    {
        int t = tid >> 4, p = tid & 15;
        const unsigned short* xr = x2 + (size_t)(tok0 + t) * 256 + p * 16;
        bf16x8 xa = *(const bf16x8*)(xr);
        bf16x8 xb = *(const bf16x8*)(xr + 8);
        float vals[16], s = 0.f, sq = 0.f;
        #pragma unroll
        for (int u = 0; u < 8; u++) { vals[u] = bf2f((unsigned short)xa[u]); vals[8 + u] = bf2f((unsigned short)xb[u]); }
        #pragma unroll
        for (int u = 0; u < 16; u++) { s += vals[u]; sq += vals[u] * vals[u]; }
        #pragma unroll
        for (int off = 1; off < 16; off <<= 1) { s += __shfl_xor(s, off); sq += __shfl_xor(sq, off); }
        float mu = s * (1.f / 256.f);
        float rs = rsqrtf(fmaxf(sq * (1.f / 256.f) - mu * mu, 0.f) + 1e-5f);
        bf16x8 o1, o2;
        #pragma unroll
        for (int u = 0; u < 8; u++) {
            o1[u] = (short)f2bf((vals[u] - mu) * rs * g2F[p * 16 + u] + b2lnF[p * 16 + u]);
            o2[u] = (short)f2bf((vals[8 + u] - mu) * rs * g2F[p * 16 + 8 + u] + b2lnF[p * 16 + 8 + u]);
        }
        *(bf16x8*)(As2 + t * 264 + p * 16) = o1;
        *(bf16x8*)(As2 + t * 264 + p * 16 + 8) = o2;
    }
    __syncthreads();

    int sr = tid >> 2, sp = (tid & 3) * 64;  // B-staging map: 64 rows x 256 k

    // ---- GEMM1: (16x256) @ w1^T -> gelu -> Hs (16x1024) ----
    for (int nc = 0; nc < 16; nc++) {
        const unsigned short* bg = w1t + (size_t)(nc * 64 + sr) * 256 + sp;
        unsigned short* bsd = Bs + sr * 264 + sp;
        #pragma unroll
        for (int i = 0; i < 8; i++)
            *(bf16x8*)(bsd + i * 8) = *(const bf16x8*)(bg + i * 8);
        __syncthreads();
        f32x4 acc;
        #pragma unroll
        for (int r = 0; r < 4; r++) acc[r] = 0.f;
        #pragma unroll
        for (int ks = 0; ks < 256; ks += 32) {
            bf16x8 af = *(const bf16x8*)(As2 + m16 * 264 + ks + q4 * 8);
            bf16x8 bfr = *(const bf16x8*)(Bs + (wv * 16 + m16) * 264 + ks + q4 * 8);
            acc = __builtin_amdgcn_mfma_f32_16x16x32_bf16(af, bfr, acc, 0, 0, 0);
        }
        int col = nc * 64 + wv * 16 + m16;
        float bb = b1F[col];
        #pragma unroll
        for (int r = 0; r < 4; r++) {
            float v = acc[r] + bb;
            float gel = 0.5f * v * (1.f + erff(v * 0.70710678118654752f));  // exact gelu
            Hs[(q4 * 4 + r) * 1032 + col] = f2bf(gel);
        }
        __syncthreads();
    }

    // ---- GEMM2: (16x1024) @ w2^T + b2 + x2 -> out ----
    for (int oc = 0; oc < 4; oc++) {
        f32x4 acc;
        #pragma unroll
        for (int r = 0; r < 4; r++) acc[r] = 0.f;
        for (int kg = 0; kg < 4; kg++) {
            __syncthreads();  // protect Bs readers from previous stage
            const unsigned short* bg = w2t + (size_t)(oc * 64 + sr) * 1024 + kg * 256 + sp;
            unsigned short* bsd = Bs + sr * 264 + sp;
            #pragma unroll
            for (int i = 0; i < 8; i++)
                *(bf16x8*)(bsd + i * 8) = *(const bf16x8*)(bg + i * 8);
            __syncthreads();
            #pragma unroll
            for (int ks = 0; ks < 256; ks += 32) {
                bf16x8 af = *(const bf16x8*)(Hs + m16 * 1032 + kg * 256 + ks + q4 * 8);
                bf16x8 bfr = *(const bf16x8*)(Bs + (wv * 16 + m16) * 264 + ks + q4 * 8);
                acc = __builtin_amdgcn_mfma_f32_16x16x32_bf16(af, bfr, acc, 0, 0, 0);
            }
        }
        int col = oc * 64 + wv * 16 + m16;
        float bb = b2F[col];
        #pragma unroll
        for (int r = 0; r < 4; r++) {
            int tokr = tok0 + q4 * 4 + r;
            size_t idx = (size_t)tokr * 256 + col;
            float v = acc[r] + bb + bf2f(x2[idx]);
            if (f) ((float*)out)[idx] = v;
            else   ((unsigned short*)out)[idx] = f2bf(v);
        }
    }
}

// ------------------------------- launcher ----------------------------------
extern "C" void kernel_launch(void* const* d_in, const int* in_sizes, int n_in,
                              void* d_out, int out_size, void* d_ws, size_t ws_size,
                              hipStream_t stream) {
    const void* x      = d_in[0];
    const void* ln1_g  = d_in[1];
    const void* ln1_b  = d_in[2];
    const void* qkv_w  = d_in[3];
    const void* qkv_b  = d_in[4];
    const void* rpb    = d_in[5];
    const void* proj_w = d_in[6];
    const void* proj_b = d_in[7];
    const void* ln2_g  = d_in[8];
    const void* ln2_b  = d_in[9];
    const void* w1     = d_in[10];
    const void* b1     = d_in[11];
    const void* w2     = d_in[12];
    const void* b2     = d_in[13];

    char* ws = (char*)d_ws;
    size_t off = 0;
    unsigned short* y = (unsigned short*)(ws + off);       // LN1 out; reused as attn out
    off += (size_t)NTOK * 256 * 2;
    size_t qkv_off = off;
    unsigned short* qkv = (unsigned short*)(ws + off);     // (NTOK,768) bf16
    off += (size_t)NTOK * 768 * 2;
    unsigned short* x2 = (unsigned short*)(ws + qkv_off);  // overlaps qkv (dead by then)
    unsigned short* o = y;                                 // overlaps y (dead after QKV GEMM)
    unsigned short* qkvWt = (unsigned short*)(ws + off); off += 768 * 256 * 2;
    unsigned short* projWt = (unsigned short*)(ws + off); off += 256 * 256 * 2;
    unsigned short* w1t = (unsigned short*)(ws + off); off += 1024 * 256 * 2;
    unsigned short* w2t = (unsigned short*)(ws + off); off += 256 * 1024 * 2;
    float* paramsF = (float*)(ws + off); off += NPARAM * 4;
    int* flag = (int*)(ws + off); off += 16;
    (void)ws_size; (void)in_sizes; (void)n_in; (void)out_size;

    detect_kernel<<<1, 64, 0, stream>>>((const unsigned short*)x, flag);
    convert_params_kernel<<<(NPARAM + 255) / 256, 256, 0, stream>>>(
        ln1_g, ln1_b, qkv_b, proj_b, ln2_g, ln2_b, b1, b2, rpb, flag, paramsF);
    transpose_any<<<(256 * 768 + 255) / 256, 256, 0, stream>>>(qkv_w, qkvWt, 256, 768, flag);
    transpose_any<<<(256 * 256 + 255) / 256, 256, 0, stream>>>(proj_w, projWt, 256, 256, flag);
    transpose_any<<<(256 * 1024 + 255) / 256, 256, 0, stream>>>(w1, w1t, 256, 1024, flag);
    transpose_any<<<(1024 * 256 + 255) / 256, 256, 0, stream>>>(w2, w2t, 1024, 256, flag);

    ln1_window_kernel<<<NTOK / 4, 256, 0, stream>>>(x, paramsF, y, flag);
    gemm_qkv_kernel<<<dim3(768 / 64, NTOK / 128), 256, 0, stream>>>(y, qkvWt, paramsF + 512, qkv);
    attn_kernel<<<4096 * 8, 256, 0, stream>>>(qkv, paramsF + 3328, o);
    gemm_proj_kernel<<<dim3(256 / 64, NTOK / 128), 256, 0, stream>>>(
        o, projWt, paramsF + 1280, x, x2, flag);
    mlp_fused_kernel<<<NTOK / 16, 256, 0, stream>>>(
        x2, paramsF + 1536, paramsF + 1792, w1t, paramsF + 2048, w2t, paramsF + 3072, d_out, flag);
}

// Round 3
// 1752.825 us; speedup vs baseline: 1.7256x; 1.7256x over previous
//
#include <hip/hip_runtime.h>
#include <math.h>

// ---------------------------------------------------------------------------
// Swin block: B=64 H=W=56 C=256 WIN=7 SHIFT=3 HEADS=8 HD=32.
// Input/output dtype (fp32 vs bf16) detected at runtime; bf16 MFMA pipeline.
// Round 3: MLP rewritten as chunked-fused GEMM (A in regs, hidden in 32-chunks,
// fp32 out-accumulators persistent in regs). Other kernels unchanged.
// ---------------------------------------------------------------------------

typedef __attribute__((ext_vector_type(8))) short bf16x8;   // 8 bf16 = 4 VGPRs
typedef __attribute__((ext_vector_type(4))) float f32x4;

#define NTOK 200704   // 64*56*56
#define NN   49
#define NPARAM 4680   // fp32 param block element count

__device__ __forceinline__ float bf2f(unsigned short u) {
    union { unsigned int i; float f; } v; v.i = ((unsigned)u) << 16; return v.f;
}
__device__ __forceinline__ unsigned short f2bf(float f) {
    union { float fv; unsigned int i; } v; v.fv = f;
    return (unsigned short)((v.i + 0x7fffu + ((v.i >> 16) & 1u)) >> 16);  // RNE
}

// ------------------------------ dtype detector -----------------------------
__global__ void detect_kernel(const unsigned short* __restrict__ xu, int* flag) {
    int ln = threadIdx.x;  // 64 threads
    int sane = 0;
    #pragma unroll
    for (int t = 0; t < 16; t++) {
        unsigned u = xu[(ln * 16 + t) * 2];
        unsigned e = (u >> 7) & 0xFF;
        sane += (e >= 0x60 && e <= 0x90) ? 1 : 0;
    }
    #pragma unroll
    for (int off = 32; off; off >>= 1) sane += __shfl_xor(sane, off);
    if (ln == 0) *flag = (sane < 614) ? 1 : 0;
}

__device__ __forceinline__ float ld_any(const void* p, int j, int f) {
    return f ? ((const float*)p)[j] : bf2f(((const unsigned short*)p)[j]);
}

// ------------------------ small params -> fp32 block -----------------------
__global__ void convert_params_kernel(
    const void* ln1_g, const void* ln1_b, const void* qkv_b, const void* proj_b,
    const void* ln2_g, const void* ln2_b, const void* b1, const void* b2,
    const void* rpb, const int* __restrict__ flag, float* __restrict__ dst) {
    int i = blockIdx.x * 256 + threadIdx.x;
    if (i >= NPARAM) return;
    int f = *flag;
    const void* src; int j;
    if      (i < 256)  { src = ln1_g;  j = i; }
    else if (i < 512)  { src = ln1_b;  j = i - 256; }
    else if (i < 1280) { src = qkv_b;  j = i - 512; }
    else if (i < 1536) { src = proj_b; j = i - 1280; }
    else if (i < 1792) { src = ln2_g;  j = i - 1536; }
    else if (i < 2048) { src = ln2_b;  j = i - 1792; }
    else if (i < 3072) { src = b1;     j = i - 2048; }
    else if (i < 3328) { src = b2;     j = i - 3072; }
    else               { src = rpb;    j = i - 3328; }
    dst[i] = ld_any(src, j, f);
}

// --------------------- weight transpose (any dtype -> bf16) ----------------
// in: (K,N) row-major -> out: (N,K) row-major bf16
__global__ void transpose_any(const void* __restrict__ in,
                              unsigned short* __restrict__ out, int K, int N,
                              const int* __restrict__ flag) {
    int f = *flag;
    int idx = blockIdx.x * 256 + threadIdx.x;
    if (idx < K * N) {
        int k = idx / N, n = idx - k * N;
        out[n * K + k] = f2bf(ld_any(in, idx, f));
    }
}

// ------------- w2 (1024,256) -> k-chunk-major blocks (32 x [256n x 32k]) ---
// dst[c*8192 + n*32 + kk] = w2[(c*32+kk)*256 + n]
__global__ void relayout_w2(const void* __restrict__ in,
                            unsigned short* __restrict__ out,
                            const int* __restrict__ flag) {
    int f = *flag;
    int idx = blockIdx.x * 256 + threadIdx.x;  // over 1024*256
    if (idx < 1024 * 256) {
        int k = idx >> 8, n = idx & 255;
        int c = k >> 5, kk = k & 31;
        out[c * 8192 + n * 32 + kk] = f2bf(ld_any(in, idx, f));
    }
}

// ------------------------- LN1 + shift + window partition ------------------
__global__ __launch_bounds__(256) void ln1_window_kernel(
    const void* __restrict__ x, const float* __restrict__ paramsF,
    unsigned short* __restrict__ y, const int* __restrict__ flag) {
    int f = *flag;
    int wv = threadIdx.x >> 6, ln = threadIdx.x & 63;
    int tok = blockIdx.x * 4 + wv;
    float v0, v1, v2, v3;
    if (f) {
        float4 pv = *(const float4*)((const float*)x + (size_t)tok * 256 + ln * 4);
        v0 = pv.x; v1 = pv.y; v2 = pv.z; v3 = pv.w;
    } else {
        ushort4 pv = *(const ushort4*)((const unsigned short*)x + (size_t)tok * 256 + ln * 4);
        v0 = bf2f(pv.x); v1 = bf2f(pv.y); v2 = bf2f(pv.z); v3 = bf2f(pv.w);
    }
    float s = v0 + v1 + v2 + v3;
    float sq = v0 * v0 + v1 * v1 + v2 * v2 + v3 * v3;
    #pragma unroll
    for (int off = 32; off; off >>= 1) { s += __shfl_xor(s, off); sq += __shfl_xor(sq, off); }
    float mu = s * (1.f / 256.f);
    float rs = rsqrtf(fmaxf(sq * (1.f / 256.f) - mu * mu, 0.f) + 1e-5f);
    float4 gv = *(const float4*)(paramsF + ln * 4);        // ln1_g
    float4 bv = *(const float4*)(paramsF + 256 + ln * 4);  // ln1_b
    int bb = tok / 3136, hw = tok - bb * 3136;
    int h = hw / 56, w = hw - h * 56;
    int hp = h - 3; hp += (hp < 0) ? 56 : 0;
    int wp = w - 3; wp += (wp < 0) ? 56 : 0;
    int win = (hp / 7) * 8 + (wp / 7);
    int n = (hp % 7) * 7 + (wp % 7);
    size_t drow = ((size_t)bb * 64 + win) * NN + n;
    ushort4 o;
    o.x = f2bf((v0 - mu) * rs * gv.x + bv.x);
    o.y = f2bf((v1 - mu) * rs * gv.y + bv.y);
    o.z = f2bf((v2 - mu) * rs * gv.z + bv.z);
    o.w = f2bf((v3 - mu) * rs * gv.w + bv.w);
    *(ushort4*)(y + drow * 256 + ln * 4) = o;
}

// ------------------------------ GEMM core (K=256) --------------------------
__device__ __forceinline__ void gemm_core_k256(
    const unsigned short* __restrict__ A, const unsigned short* __restrict__ Bt,
    int rowBase, int colBase, unsigned short* As, unsigned short* Bs, f32x4 acc[2][4]) {
    const int tid = threadIdx.x;
    const int wv = tid >> 6, ln = tid & 63;
    const int m16 = ln & 15, q4 = ln >> 4;
    const int ar = tid >> 1, ah = (tid & 1) * 32;
    const int br = tid >> 2, bp = (tid & 3) * 16;
    for (int kb = 0; kb < 256; kb += 64) {
        const unsigned short* ag = A + (size_t)(rowBase + ar) * 256 + kb + ah;
        unsigned short* asd = As + ar * 72 + ah;
        #pragma unroll
        for (int i = 0; i < 4; i++)
            *(bf16x8*)(asd + i * 8) = *(const bf16x8*)(ag + i * 8);
        const unsigned short* bg = Bt + (size_t)(colBase + br) * 256 + kb + bp;
        unsigned short* bsd = Bs + br * 72 + bp;
        #pragma unroll
        for (int i = 0; i < 2; i++)
            *(bf16x8*)(bsd + i * 8) = *(const bf16x8*)(bg + i * 8);
        __syncthreads();
        #pragma unroll
        for (int ks = 0; ks < 64; ks += 32) {
            bf16x8 af[2], bfr[4];
            #pragma unroll
            for (int rt = 0; rt < 2; rt++)
                af[rt] = *(const bf16x8*)(As + (wv * 32 + rt * 16 + m16) * 72 + ks + q4 * 8);
            #pragma unroll
            for (int ct = 0; ct < 4; ct++)
                bfr[ct] = *(const bf16x8*)(Bs + (ct * 16 + m16) * 72 + ks + q4 * 8);
            #pragma unroll
            for (int rt = 0; rt < 2; rt++)
                #pragma unroll
                for (int ct = 0; ct < 4; ct++)
                    acc[rt][ct] = __builtin_amdgcn_mfma_f32_16x16x32_bf16(
                        af[rt], bfr[ct], acc[rt][ct], 0, 0, 0);
        }
        __syncthreads();
    }
}

// ------------------------------- GEMM: QKV ---------------------------------
__global__ __launch_bounds__(256) void gemm_qkv_kernel(
    const unsigned short* __restrict__ A, const unsigned short* __restrict__ Bt,
    const float* __restrict__ bias,  // qkv_b fp32 (768)
    unsigned short* __restrict__ out) {
    __shared__ unsigned short As[128 * 72];
    __shared__ unsigned short Bs[64 * 72];
    const int ln = threadIdx.x & 63, wv = threadIdx.x >> 6;
    const int m16 = ln & 15, q4 = ln >> 4;
    const int rowBase = blockIdx.y * 128, colBase = blockIdx.x * 64;
    f32x4 acc[2][4];
    #pragma unroll
    for (int i = 0; i < 2; i++)
        #pragma unroll
        for (int j = 0; j < 4; j++)
            #pragma unroll
            for (int r = 0; r < 4; r++) acc[i][j][r] = 0.f;
    gemm_core_k256(A, Bt, rowBase, colBase, As, Bs, acc);
    #pragma unroll
    for (int rt = 0; rt < 2; rt++)
        #pragma unroll
        for (int ct = 0; ct < 4; ct++) {
            int col = colBase + ct * 16 + m16;
            float bs = bias[col];
            float scale = (col < 256) ? 0.17677669529663689f : 1.0f;  // q * HD^-0.5
            #pragma unroll
            for (int r = 0; r < 4; r++) {
                int row = rowBase + wv * 32 + rt * 16 + q4 * 4 + r;
                out[(size_t)row * 768 + col] = f2bf((acc[rt][ct][r] + bs) * scale);
            }
        }
}

// ------------------------- GEMM: proj + scatter + residual -----------------
__global__ __launch_bounds__(256) void gemm_proj_kernel(
    const unsigned short* __restrict__ A, const unsigned short* __restrict__ Bt,
    const float* __restrict__ bias,  // proj_b fp32
    const void* __restrict__ xin,    // x natural order (flag dtype)
    unsigned short* __restrict__ x2, const int* __restrict__ flag) {
    __shared__ unsigned short As[128 * 72];
    __shared__ unsigned short Bs[64 * 72];
    const int f = *flag;
    const int ln = threadIdx.x & 63, wv = threadIdx.x >> 6;
    const int m16 = ln & 15, q4 = ln >> 4;
    const int rowBase = blockIdx.y * 128, colBase = blockIdx.x * 64;
    f32x4 acc[2][4];
    #pragma unroll
    for (int i = 0; i < 2; i++)
        #pragma unroll
        for (int j = 0; j < 4; j++)
            #pragma unroll
            for (int r = 0; r < 4; r++) acc[i][j][r] = 0.f;
    gemm_core_k256(A, Bt, rowBase, colBase, As, Bs, acc);
    #pragma unroll
    for (int rt = 0; rt < 2; rt++)
        #pragma unroll
        for (int r = 0; r < 4; r++) {
            int row = rowBase + wv * 32 + rt * 16 + q4 * 4 + r;  // window-order token
            int win = row / NN, n = row - win * NN;
            int bb = win >> 6, wl = win & 63;
            int i7 = n / 7, j7 = n - i7 * 7;
            int hp = (wl >> 3) * 7 + i7 + 3; if (hp >= 56) hp -= 56;  // un-shift
            int wp = (wl & 7) * 7 + j7 + 3;  if (wp >= 56) wp -= 56;
            size_t drow = ((size_t)bb * 3136 + hp * 56 + wp) * 256;
            #pragma unroll
            for (int ct = 0; ct < 4; ct++) {
                int col = colBase + ct * 16 + m16;
                float v = acc[rt][ct][r] + bias[col] + ld_any(xin, drow + col, f);
                x2[drow + col] = f2bf(v);
            }
        }
}

// ------------------------------- attention ---------------------------------
__global__ __launch_bounds__(256) void attn_kernel(
    const unsigned short* __restrict__ qkv,  // (NTOK,768): [q|k|v] x head x d
    const float* __restrict__ rpbF,          // (169*8) fp32
    unsigned short* __restrict__ o) {        // (NTOK,256) window order
    __shared__ unsigned short Qs[49 * 40], Ks[49 * 40], Vs[49 * 40];
    __shared__ float S[49 * 52];
    int tid = threadIdx.x;
    int win = blockIdx.x >> 3, head = blockIdx.x & 7;
    size_t base = (size_t)win * 49 * 768 + head * 32;
    if (tid < 196) {
        int i = tid >> 2, part = (tid & 3) * 8;
        *(bf16x8*)(Qs + i * 40 + part) = *(const bf16x8*)(qkv + base + (size_t)i * 768 + part);
        *(bf16x8*)(Ks + i * 40 + part) = *(const bf16x8*)(qkv + base + 256 + (size_t)i * 768 + part);
        *(bf16x8*)(Vs + i * 40 + part) = *(const bf16x8*)(qkv + base + 512 + (size_t)i * 768 + part);
    }
    __syncthreads();
    int wl = win & 63;
    int wh0 = (wl >> 3) * 7, ww0 = (wl & 7) * 7;
    for (int e = tid; e < 2401; e += 256) {
        int i = e / 49, j = e - i * 49;
        float a = 0.f;
        #pragma unroll
        for (int dd = 0; dd < 32; dd += 8) {
            bf16x8 qv = *(const bf16x8*)(Qs + i * 40 + dd);
            bf16x8 kv = *(const bf16x8*)(Ks + j * 40 + dd);
            #pragma unroll
            for (int u = 0; u < 8; u++)
                a += bf2f((unsigned short)qv[u]) * bf2f((unsigned short)kv[u]);
        }
        int ir = i / 7, ic = i - ir * 7, jr = j / 7, jc = j - jr * 7;
        a += rpbF[((ir - jr + 6) * 13 + (ic - jc + 6)) * 8 + head];
        int hi = wh0 + ir, wi = ww0 + ic, hj = wh0 + jr, wj = ww0 + jc;
        int ci = (hi < 49 ? 0 : (hi < 53 ? 3 : 6)) + (wi < 49 ? 0 : (wi < 53 ? 1 : 2));
        int cj = (hj < 49 ? 0 : (hj < 53 ? 3 : 6)) + (wj < 49 ? 0 : (wj < 53 ? 1 : 2));
        if (ci != cj) a -= 100.f;
        S[i * 52 + j] = a;
    }
    __syncthreads();
    if (tid < 49) {
        float m = -1e30f;
        for (int j = 0; j < 49; j++) m = fmaxf(m, S[tid * 52 + j]);
        float s = 0.f;
        for (int j = 0; j < 49; j++) { float e = expf(S[tid * 52 + j] - m); S[tid * 52 + j] = e; s += e; }
        float inv = 1.f / s;
        for (int j = 0; j < 49; j++) S[tid * 52 + j] *= inv;
    }
    __syncthreads();
    if (tid < 196) {
        int i = tid >> 2, dr = (tid & 3) * 8;
        float a[8];
        #pragma unroll
        for (int u = 0; u < 8; u++) a[u] = 0.f;
        for (int j = 0; j < 49; j++) {
            float pp = S[i * 52 + j];
            bf16x8 vv = *(const bf16x8*)(Vs + j * 40 + dr);
            #pragma unroll
            for (int u = 0; u < 8; u++) a[u] += pp * bf2f((unsigned short)vv[u]);
        }
        bf16x8 ov;
        #pragma unroll
        for (int u = 0; u < 8; u++) ov[u] = (short)f2bf(a[u]);
        *(bf16x8*)(o + ((size_t)win * 49 + i) * 256 + head * 32 + dr) = ov;
    }
}

// ---------------- fused LN2 + MLP + residual, v2 (chunked) -----------------
// 64 tokens/block, 4 waves. A (LN2 of x2) lives in registers (wave w owns
// tokens [16w,16w+16)). Hidden dim processed in 32 chunks of 32:
//   GEMM1 chunk (64x32x256) -> gelu -> Hs -> GEMM2 partial (64x256x32)
// accumulated into persistent fp32 regs. out = acc + b2 + x2 residual.
__global__ __launch_bounds__(256, 2) void mlp_fused_v2(
    const unsigned short* __restrict__ x2,
    const float* __restrict__ g2F, const float* __restrict__ b2lnF,
    const unsigned short* __restrict__ w1t,  // (1024,256) n-major
    const float* __restrict__ b1F,
    const unsigned short* __restrict__ w2s,  // 32 chunks of [256n x 32k]
    const float* __restrict__ b2F,
    void* __restrict__ out, const int* __restrict__ flag) {
    __shared__ unsigned short Bs1[32 * 264];  // w1 slice: 32 hidden rows x 256 k
    __shared__ unsigned short Bs2[256 * 40];  // w2 slice: 256 out cols x 32 k
    __shared__ unsigned short Hs[64 * 40];    // gelu: 64 tokens x 32 hidden
    const int f = *flag;
    const int tid = threadIdx.x;
    const int wv = tid >> 6, ln = tid & 63;
    const int m16 = ln & 15, q4 = ln >> 4;
    const int tok0 = blockIdx.x * 64;

    // ---- load x2 rows + LN2 -> areg (A-operand fragments, all 8 k-steps) ----
    bf16x8 areg[8];
    {
        const unsigned short* xr = x2 + (size_t)(tok0 + wv * 16 + m16) * 256 + q4 * 8;
        #pragma unroll
        for (int ks = 0; ks < 8; ks++) areg[ks] = *(const bf16x8*)(xr + ks * 32);
        float s = 0.f, sq = 0.f;
        #pragma unroll
        for (int ks = 0; ks < 8; ks++)
            #pragma unroll
            for (int u = 0; u < 8; u++) {
                float v = bf2f((unsigned short)areg[ks][u]);
                s += v; sq += v * v;
            }
        s += __shfl_xor(s, 16); s += __shfl_xor(s, 32);
        sq += __shfl_xor(sq, 16); sq += __shfl_xor(sq, 32);
        float mu = s * (1.f / 256.f);
        float rs = rsqrtf(fmaxf(sq * (1.f / 256.f) - mu * mu, 0.f) + 1e-5f);
        #pragma unroll
        for (int ks = 0; ks < 8; ks++)
            #pragma unroll
            for (int u = 0; u < 8; u++) {
                int kidx = ks * 32 + q4 * 8 + u;
                float v = (bf2f((unsigned short)areg[ks][u]) - mu) * rs * g2F[kidx] + b2lnF[kidx];
                areg[ks][u] = (short)f2bf(v);
            }
    }

    f32x4 acc2[4][4];
    #pragma unroll
    for (int rt = 0; rt < 4; rt++)
        #pragma unroll
        for (int ct = 0; ct < 4; ct++)
            #pragma unroll
            for (int r = 0; r < 4; r++) acc2[rt][ct][r] = 0.f;

    // staging maps
    const int s1r = tid >> 3, s1p = (tid & 7) * 32;  // Bs1: 32 rows x 256 k

    for (int c = 0; c < 32; c++) {
        // ---- stage w1 slice (rows c*32..c*32+31, all 256 k) ----
        {
            const unsigned short* bg = w1t + (size_t)(c * 32 + s1r) * 256 + s1p;
            unsigned short* bsd = Bs1 + s1r * 264 + s1p;
            #pragma unroll
            for (int i = 0; i < 4; i++)
                *(bf16x8*)(bsd + i * 8) = *(const bf16x8*)(bg + i * 8);
        }
        // ---- stage w2 slice (chunk-contiguous; row tid = out col, 32 k) ----
        {
            const unsigned short* bg = w2s + (size_t)c * 8192 + tid * 32;
            unsigned short* bsd = Bs2 + tid * 40;
            #pragma unroll
            for (int i = 0; i < 4; i++)
                *(bf16x8*)(bsd + i * 8) = *(const bf16x8*)(bg + i * 8);
        }
        __syncthreads();

        // ---- GEMM1: wave w -> tokens [16w,+16) x 32 chunk cols ----
        f32x4 acc1[2];
        #pragma unroll
        for (int ct = 0; ct < 2; ct++)
            #pragma unroll
            for (int r = 0; r < 4; r++) acc1[ct][r] = 0.f;
        #pragma unroll
        for (int ks = 0; ks < 8; ks++) {
            #pragma unroll
            for (int ct = 0; ct < 2; ct++) {
                bf16x8 bfr = *(const bf16x8*)(Bs1 + (ct * 16 + m16) * 264 + ks * 32 + q4 * 8);
                acc1[ct] = __builtin_amdgcn_mfma_f32_16x16x32_bf16(areg[ks], bfr, acc1[ct], 0, 0, 0);
            }
        }
        // gelu -> Hs
        #pragma unroll
        for (int ct = 0; ct < 2; ct++) {
            float bb = b1F[c * 32 + ct * 16 + m16];
            #pragma unroll
            for (int r = 0; r < 4; r++) {
                float v = acc1[ct][r] + bb;
                float gel = 0.5f * v * (1.f + erff(v * 0.70710678118654752f));
                Hs[(wv * 16 + q4 * 4 + r) * 40 + ct * 16 + m16] = f2bf(gel);
            }
        }
        __syncthreads();

        // ---- GEMM2 partial: K=32 chunk; wave w -> out cols [64w,+64) ----
        bf16x8 haf[4];
        #pragma unroll
        for (int rt = 0; rt < 4; rt++)
            haf[rt] = *(const bf16x8*)(Hs + (rt * 16 + m16) * 40 + q4 * 8);
        #pragma unroll
        for (int ct = 0; ct < 4; ct++) {
            bf16x8 bfr = *(const bf16x8*)(Bs2 + (wv * 64 + ct * 16 + m16) * 40 + q4 * 8);
            #pragma unroll
            for (int rt = 0; rt < 4; rt++)
                acc2[rt][ct] = __builtin_amdgcn_mfma_f32_16x16x32_bf16(haf[rt], bfr, acc2[rt][ct], 0, 0, 0);
        }
        __syncthreads();
    }

    // ---- epilogue: + b2 + residual, store ----
    #pragma unroll
    for (int rt = 0; rt < 4; rt++)
        #pragma unroll
        for (int ct = 0; ct < 4; ct++) {
            int col = wv * 64 + ct * 16 + m16;
            float bb = b2F[col];
            #pragma unroll
            for (int r = 0; r < 4; r++) {
                int tokr = tok0 + rt * 16 + q4 * 4 + r;
                size_t idx = (size_t)tokr * 256 + col;
                float v = acc2[rt][ct][r] + bb + bf2f(x2[idx]);
                if (f) ((float*)out)[idx] = v;
                else   ((unsigned short*)out)[idx] = f2bf(v);
            }
        }
}

// ------------------------------- launcher ----------------------------------
extern "C" void kernel_launch(void* const* d_in, const int* in_sizes, int n_in,
                              void* d_out, int out_size, void* d_ws, size_t ws_size,
                              hipStream_t stream) {
    const void* x      = d_in[0];
    const void* qkv_w  = d_in[3];
    const void* proj_w = d_in[6];
    const void* w1     = d_in[10];
    const void* w2     = d_in[12];

    char* ws = (char*)d_ws;
    size_t off = 0;
    unsigned short* y = (unsigned short*)(ws + off);       // LN1 out; reused as attn out
    off += (size_t)NTOK * 256 * 2;
    size_t qkv_off = off;
    unsigned short* qkv = (unsigned short*)(ws + off);     // (NTOK,768) bf16
    off += (size_t)NTOK * 768 * 2;
    unsigned short* x2 = (unsigned short*)(ws + qkv_off);  // overlaps qkv (dead by then)
    unsigned short* o = y;                                 // overlaps y (dead after QKV GEMM)
    unsigned short* qkvWt = (unsigned short*)(ws + off); off += 768 * 256 * 2;
    unsigned short* projWt = (unsigned short*)(ws + off); off += 256 * 256 * 2;
    unsigned short* w1t = (unsigned short*)(ws + off); off += 1024 * 256 * 2;
    unsigned short* w2s = (unsigned short*)(ws + off); off += 256 * 1024 * 2;
    float* paramsF = (float*)(ws + off); off += NPARAM * 4;
    int* flag = (int*)(ws + off); off += 16;
    (void)ws_size; (void)in_sizes; (void)n_in; (void)out_size;

    detect_kernel<<<1, 64, 0, stream>>>((const unsigned short*)x, flag);
    convert_params_kernel<<<(NPARAM + 255) / 256, 256, 0, stream>>>(
        d_in[1], d_in[2], d_in[4], d_in[7], d_in[8], d_in[9], d_in[11], d_in[13],
        d_in[5], flag, paramsF);
    transpose_any<<<(256 * 768 + 255) / 256, 256, 0, stream>>>(qkv_w, qkvWt, 256, 768, flag);
    transpose_any<<<(256 * 256 + 255) / 256, 256, 0, stream>>>(proj_w, projWt, 256, 256, flag);
    transpose_any<<<(256 * 1024 + 255) / 256, 256, 0, stream>>>(w1, w1t, 256, 1024, flag);
    relayout_w2<<<(1024 * 256 + 255) / 256, 256, 0, stream>>>(w2, w2s, flag);

    ln1_window_kernel<<<NTOK / 4, 256, 0, stream>>>(x, paramsF, y, flag);
    gemm_qkv_kernel<<<dim3(768 / 64, NTOK / 128), 256, 0, stream>>>(y, qkvWt, paramsF + 512, qkv);
    attn_kernel<<<4096 * 8, 256, 0, stream>>>(qkv, paramsF + 3328, o);
    gemm_proj_kernel<<<dim3(256 / 64, NTOK / 128), 256, 0, stream>>>(
        o, projWt, paramsF + 1280, x, x2, flag);
    mlp_fused_v2<<<NTOK / 64, 256, 0, stream>>>(
        x2, paramsF + 1536, paramsF + 1792, w1t, paramsF + 2048, w2s, paramsF + 3072, d_out, flag);
}